// Round 1
// baseline (458.977 us; speedup 1.0000x reference)
//
#include <hip/hip_runtime.h>

typedef float f32x4 __attribute__((ext_vector_type(4)));
typedef short bf16x8 __attribute__((ext_vector_type(8)));

__device__ inline unsigned short f2bf(float f) {
    unsigned int u = __builtin_bit_cast(unsigned int, f);
    unsigned int r = (u + 0x7FFFu + ((u >> 16) & 1u)) >> 16;
    return (unsigned short)r;
}

// ---------------- Precompute: T0/T1/T2 = tok_emb @ W0/W1/W2  (each 1024x256 f32)
__global__ __launch_bounds__(256) void k_ttables(const float* __restrict__ tok,
                                                 const float* __restrict__ W,
                                                 float* __restrict__ T) {
    __shared__ float s_tok[16][256];
    int r0 = blockIdx.x * 16;
    for (int t = threadIdx.x; t < 16 * 256; t += 256)
        s_tok[t >> 8][t & 255] = tok[(r0 + (t >> 8)) * 256 + (t & 255)];
    __syncthreads();
    int j = threadIdx.x;
    float a0[16] = {}, a1[16] = {}, a2[16] = {};
    for (int k = 0; k < 256; k++) {
        float w0 = W[k * 256 + j];
        float w1 = W[(256 + k) * 256 + j];
        float w2 = W[(512 + k) * 256 + j];
#pragma unroll
        for (int r = 0; r < 16; r++) {
            float x = s_tok[r][k];
            a0[r] += x * w0;
            a1[r] += x * w1;
            a2[r] += x * w2;
        }
    }
    for (int r = 0; r < 16; r++) {
        T[(r0 + r) * 256 + j] = a0[r];
        T[1024 * 256 + (r0 + r) * 256 + j] = a1[r];
        T[2 * 1024 * 256 + (r0 + r) * 256 + j] = a2[r];
    }
}

// ---------------- Precompute: per-level constant vectors carr[d][256]
// carr[d] = dep[d+1]@(W3+W5) + idx0@W4 + idx1@W6 + b ;  carr[13] += dep[14]@(W1+W2)
__global__ __launch_bounds__(256) void k_carr(const float* __restrict__ dep,
                                              const float* __restrict__ idx,
                                              const float* __restrict__ W,
                                              const float* __restrict__ bvec,
                                              float* __restrict__ carr) {
    int d = blockIdx.x;  // 0..13
    int j = threadIdx.x;
    float acc = bvec[j];
    for (int k = 0; k < 256; k++) {
        float dv = dep[(d + 1) * 256 + k];
        acc += dv * (W[(768 + k) * 256 + j] + W[(1280 + k) * 256 + j]);
        acc += idx[k] * W[(1024 + k) * 256 + j];
        acc += idx[256 + k] * W[(1536 + k) * 256 + j];
    }
    if (d == 13) {
        for (int k = 0; k < 256; k++) {
            float dv = dep[14 * 256 + k];
            acc += dv * (W[(256 + k) * 256 + j] + W[(512 + k) * 256 + j]);
        }
    }
    carr[d * 256 + j] = acc;
}

// ---------------- Precompute: W12T[n][k] = bf16(W[256+k][n]),  256x512 bf16
__global__ __launch_bounds__(256) void k_w12t(const float* __restrict__ W,
                                              unsigned short* __restrict__ W12T) {
    int idx = blockIdx.x * 256 + threadIdx.x;  // 0..131071
    int nn = idx >> 9, k = idx & 511;
    W12T[idx] = f2bf(W[(256 + k) * 256 + nn]);
}

// ---------------- Level 13: pure gather + relu + LN.  one wave per node.
__global__ __launch_bounds__(256) void k_level13(const int* __restrict__ leaf_ids,
                                                 const int* __restrict__ op_ids,
                                                 const float* __restrict__ T0,
                                                 const float* __restrict__ T1,
                                                 const float* __restrict__ T2,
                                                 const float* __restrict__ carr,
                                                 const float* __restrict__ gamma,
                                                 const float* __restrict__ beta,
                                                 unsigned short* __restrict__ out) {
    int wid = threadIdx.x >> 6, lane = threadIdx.x & 63;
    int node = blockIdx.x * 4 + wid;  // 0..65535
    int b = node >> 13;
    int i = node & 8191;
    int nid = op_ids[b * 16383 + 8191 + i];
    int ll = leaf_ids[b * 16384 + 2 * i];
    int lr = leaf_ids[b * 16384 + 2 * i + 1];
    const float* c13 = carr + 13 * 256;
    float v[4];
    float s = 0.f, s2 = 0.f;
#pragma unroll
    for (int q = 0; q < 4; q++) {
        int c = q * 64 + lane;
        float x = T0[nid * 256 + c] + T1[ll * 256 + c] + T2[lr * 256 + c] + c13[c];
        x = fmaxf(x, 0.f);
        v[q] = x;
        s += x;
        s2 += x * x;
    }
#pragma unroll
    for (int m = 1; m < 64; m <<= 1) {
        s += __shfl_xor(s, m);
        s2 += __shfl_xor(s2, m);
    }
    float mu = s * (1.f / 256.f);
    float var = s2 * (1.f / 256.f) - mu * mu;
    float rs = rsqrtf(var + 1e-5f);
    unsigned short* o = out + (long)node * 256;
#pragma unroll
    for (int q = 0; q < 4; q++) {
        int c = q * 64 + lane;
        float y = (v[q] - mu) * rs * gamma[c] + beta[c];
        o[c] = f2bf(y);
    }
}

// ---------------- Levels 12..0: MFMA GEMM (M=n per batch, K=512, N=256) + gather + relu + LN
__global__ __launch_bounds__(256) void k_level(const unsigned short* __restrict__ ebuf_prev,
                                               unsigned short* __restrict__ ebuf_out,
                                               const int* __restrict__ op_ids,
                                               const float* __restrict__ T0,
                                               const float* __restrict__ carr_d,
                                               const float* __restrict__ gamma,
                                               const float* __restrict__ beta,
                                               const unsigned short* __restrict__ W12T,
                                               int n, float* __restrict__ out_f32) {
    int wid = threadIdx.x >> 6, lane = threadIdx.x & 63;
    int b = blockIdx.y;
    int row0 = blockIdx.x * 64;
    int l15 = lane & 15, l4 = lane >> 4;

    __shared__ int s_nid[64];
    __shared__ float s_part[4][64][2];

    if (threadIdx.x < 64) {
        int i = row0 + threadIdx.x;
        int id = 0;
        if (i < n) id = op_ids[b * 16383 + (n - 1) + i];
        s_nid[threadIdx.x] = id;
    }
    __syncthreads();

    // X = prev emb for batch b, viewed as rows of 512 bf16 (left|right contiguous)
    const unsigned short* X = ebuf_prev + (long)b * (2 * (long)n) * 256;

    f32x4 acc[4][4] = {};

    for (int kk = 0; kk < 16; kk++) {
        int k0 = kk * 32 + l4 * 8;
        bf16x8 af[4], bfr[4];
#pragma unroll
        for (int mi = 0; mi < 4; mi++) {
            int r = row0 + mi * 16 + l15;
            af[mi] = *(const bf16x8*)(X + (long)r * 512 + k0);
        }
#pragma unroll
        for (int ni = 0; ni < 4; ni++) {
            int cn = wid * 64 + ni * 16 + l15;
            bfr[ni] = *(const bf16x8*)(W12T + (long)cn * 512 + k0);
        }
#pragma unroll
        for (int mi = 0; mi < 4; mi++)
#pragma unroll
            for (int ni = 0; ni < 4; ni++)
                acc[mi][ni] = __builtin_amdgcn_mfma_f32_16x16x32_bf16(af[mi], bfr[ni],
                                                                     acc[mi][ni], 0, 0, 0);
    }

    // epilogue constants for this wave's 64 columns
    float cv[4], gv[4], bv[4];
#pragma unroll
    for (int ni = 0; ni < 4; ni++) {
        int c = wid * 64 + ni * 16 + l15;
        cv[ni] = carr_d[c];
        gv[ni] = gamma[c];
        bv[ni] = beta[c];
    }

    // + T0 gather + carr, relu, per-row partial sums (this wave's 64 cols)
#pragma unroll
    for (int mi = 0; mi < 4; mi++) {
#pragma unroll
        for (int r = 0; r < 4; r++) {
            int row = mi * 16 + l4 * 4 + r;
            int nid = s_nid[row];
            float s = 0.f, s2 = 0.f;
#pragma unroll
            for (int ni = 0; ni < 4; ni++) {
                int c = wid * 64 + ni * 16 + l15;
                float h = acc[mi][ni][r] + T0[nid * 256 + c] + cv[ni];
                h = fmaxf(h, 0.f);
                acc[mi][ni][r] = h;
                s += h;
                s2 += h * h;
            }
#pragma unroll
            for (int m = 1; m < 16; m <<= 1) {
                s += __shfl_xor(s, m);
                s2 += __shfl_xor(s2, m);
            }
            if (l15 == 0) {
                s_part[wid][row][0] = s;
                s_part[wid][row][1] = s2;
            }
        }
    }
    __syncthreads();

    // LN finalize + store
#pragma unroll
    for (int mi = 0; mi < 4; mi++) {
#pragma unroll
        for (int r = 0; r < 4; r++) {
            int row = mi * 16 + l4 * 4 + r;
            float s = s_part[0][row][0] + s_part[1][row][0] + s_part[2][row][0] + s_part[3][row][0];
            float s2 = s_part[0][row][1] + s_part[1][row][1] + s_part[2][row][1] + s_part[3][row][1];
            float mu = s * (1.f / 256.f);
            float rs = rsqrtf(s2 * (1.f / 256.f) - mu * mu + 1e-5f);
            int i = row0 + row;
            if (i < n) {
                if (out_f32) {
                    float* o = out_f32 + b * 256;
#pragma unroll
                    for (int ni = 0; ni < 4; ni++) {
                        int c = wid * 64 + ni * 16 + l15;
                        o[c] = (acc[mi][ni][r] - mu) * rs * gv[ni] + bv[ni];
                    }
                } else {
                    unsigned short* o = ebuf_out + ((long)b * n + i) * 256;
#pragma unroll
                    for (int ni = 0; ni < 4; ni++) {
                        int c = wid * 64 + ni * 16 + l15;
                        o[c] = f2bf((acc[mi][ni][r] - mu) * rs * gv[ni] + bv[ni]);
                    }
                }
            }
        }
    }
}

extern "C" void kernel_launch(void* const* d_in, const int* in_sizes, int n_in,
                              void* d_out, int out_size, void* d_ws, size_t ws_size,
                              hipStream_t stream) {
    const int* leaf_ids = (const int*)d_in[0];
    const int* op_ids = (const int*)d_in[1];
    const float* tok = (const float*)d_in[2];
    const float* dep = (const float*)d_in[3];
    const float* idx = (const float*)d_in[4];
    const float* W = (const float*)d_in[5];
    const float* bvec = (const float*)d_in[6];
    const float* gamma = (const float*)d_in[7];
    const float* beta = (const float*)d_in[8];
    float* out = (float*)d_out;

    char* ws = (char*)d_ws;
    float* T0 = (float*)(ws);                                          // 3 MB (T0,T1,T2)
    unsigned short* W12T = (unsigned short*)(ws + 3u * 1024 * 1024);   // 256 KB
    float* carr = (float*)(ws + 3u * 1024 * 1024 + 256 * 1024);       // 14 KB
    unsigned short* ebufA = (unsigned short*)(ws + 4u * 1024 * 1024);  // 32 MB (+pad)
    unsigned short* ebufB = (unsigned short*)(ws + 40u * 1024 * 1024); // 16 MB (+pad)

    k_ttables<<<64, 256, 0, stream>>>(tok, W, T0);
    k_carr<<<14, 256, 0, stream>>>(dep, idx, W, bvec, carr);
    k_w12t<<<512, 256, 0, stream>>>(W, W12T);

    k_level13<<<16384, 256, 0, stream>>>(leaf_ids, op_ids, T0, T0 + 1024 * 256,
                                         T0 + 2 * 1024 * 256, carr, gamma, beta, ebufA);

    unsigned short* prev = ebufA;
    unsigned short* next = ebufB;
    for (int d = 12; d >= 0; d--) {
        int n = 1 << d;
        dim3 grid((n + 63) / 64, 8);
        k_level<<<grid, 256, 0, stream>>>(prev, next, op_ids, T0, carr + d * 256, gamma, beta,
                                          W12T, n, (d == 0) ? out : nullptr);
        unsigned short* t = prev;
        prev = next;
        next = t;
    }
}

// Round 2
// 335.057 us; speedup vs baseline: 1.3698x; 1.3698x over previous
//
#include <hip/hip_runtime.h>

typedef float f32x4 __attribute__((ext_vector_type(4)));
typedef float f32x4v __attribute__((ext_vector_type(4)));
typedef short bf16x8 __attribute__((ext_vector_type(8)));

__device__ inline unsigned short f2bf(float f) {
    unsigned int u = __builtin_bit_cast(unsigned int, f);
    unsigned int r = (u + 0x7FFFu + ((u >> 16) & 1u)) >> 16;
    return (unsigned short)r;
}

// ---------------- Prep: tok (1024x256 f32) -> tokbf (bf16)
__global__ __launch_bounds__(256) void k_prep_tok(const float* __restrict__ tok,
                                                  unsigned short* __restrict__ tokbf) {
    int idx = blockIdx.x * 256 + threadIdx.x;  // 0..65535, 4 elems each
    const float4 v = *(const float4*)(tok + idx * 4);
    ushort4 o;
    o.x = f2bf(v.x); o.y = f2bf(v.y); o.z = f2bf(v.z); o.w = f2bf(v.w);
    *(ushort4*)(tokbf + idx * 4) = o;
}

// ---------------- Prep: WTbf[sec*256+j][k] = bf16(W[(sec*256+k)*256+j]), sec=0..2
// (per-section 256x256 transpose, LDS-tiled)
__global__ __launch_bounds__(256) void k_prep_wt(const float* __restrict__ W,
                                                 unsigned short* __restrict__ WTbf) {
    __shared__ float s_tile[64][65];
    int sec = blockIdx.x >> 4;
    int t = blockIdx.x & 15;
    int k0 = (t >> 2) * 64, j0 = (t & 3) * 64;
    int tx = threadIdx.x & 63, ty = threadIdx.x >> 6;
#pragma unroll
    for (int r = 0; r < 16; r++) {
        int kk = ty * 16 + r;
        s_tile[kk][tx] = W[(sec * 256 + k0 + kk) * 256 + j0 + tx];
    }
    __syncthreads();
#pragma unroll
    for (int r = 0; r < 16; r++) {
        int jj = ty * 16 + r;
        WTbf[(sec * 256 + j0 + jj) * 256 + k0 + tx] = f2bf(s_tile[tx][jj]);
    }
}

// ---------------- T tables via MFMA: T[sec][1024][256] = tokbf @ Wsec, f32 out
__global__ __launch_bounds__(256) void k_ttmm(const unsigned short* __restrict__ tokbf,
                                              const unsigned short* __restrict__ WTbf,
                                              float* __restrict__ T) {
    int wid = threadIdx.x >> 6, lane = threadIdx.x & 63;
    int l15 = lane & 15, l4 = lane >> 4;
    int row0 = blockIdx.x * 64;
    int sec = blockIdx.y;

    f32x4 acc[4][4] = {};
    for (int kk = 0; kk < 8; kk++) {
        int k0 = kk * 32 + l4 * 8;
        bf16x8 af[4], bfr[4];
#pragma unroll
        for (int mi = 0; mi < 4; mi++) {
            int r = row0 + mi * 16 + l15;
            af[mi] = *(const bf16x8*)(tokbf + (long)r * 256 + k0);
        }
#pragma unroll
        for (int ni = 0; ni < 4; ni++) {
            int cn = wid * 64 + ni * 16 + l15;
            bfr[ni] = *(const bf16x8*)(WTbf + (long)(sec * 256 + cn) * 256 + k0);
        }
#pragma unroll
        for (int mi = 0; mi < 4; mi++)
#pragma unroll
            for (int ni = 0; ni < 4; ni++)
                acc[mi][ni] = __builtin_amdgcn_mfma_f32_16x16x32_bf16(af[mi], bfr[ni],
                                                                     acc[mi][ni], 0, 0, 0);
    }
#pragma unroll
    for (int mi = 0; mi < 4; mi++)
#pragma unroll
        for (int r = 0; r < 4; r++) {
            int row = row0 + mi * 16 + l4 * 4 + r;
#pragma unroll
            for (int ni = 0; ni < 4; ni++) {
                int c = wid * 64 + ni * 16 + l15;
                T[(long)sec * 262144 + (long)row * 256 + c] = acc[mi][ni][r];
            }
        }
}

// ---------------- carr[d][256]
__global__ __launch_bounds__(256) void k_carr(const float* __restrict__ dep,
                                              const float* __restrict__ idx,
                                              const float* __restrict__ W,
                                              const float* __restrict__ bvec,
                                              float* __restrict__ carr) {
    int d = blockIdx.x;
    int j = threadIdx.x;
    float acc = bvec[j];
    for (int k = 0; k < 256; k++) {
        float dv = dep[(d + 1) * 256 + k];
        acc += dv * (W[(768 + k) * 256 + j] + W[(1280 + k) * 256 + j]);
        acc += idx[k] * W[(1024 + k) * 256 + j];
        acc += idx[256 + k] * W[(1536 + k) * 256 + j];
    }
    if (d == 13) {
        for (int k = 0; k < 256; k++) {
            float dv = dep[14 * 256 + k];
            acc += dv * (W[(256 + k) * 256 + j] + W[(512 + k) * 256 + j]);
        }
    }
    carr[d * 256 + j] = acc;
}

// ---------------- Level 13: pure gather + relu + LN. one wave per node.
__global__ __launch_bounds__(256) void k_level13(const int* __restrict__ leaf_ids,
                                                 const int* __restrict__ op_ids,
                                                 const float* __restrict__ T0,
                                                 const float* __restrict__ T1,
                                                 const float* __restrict__ T2,
                                                 const float* __restrict__ carr,
                                                 const float* __restrict__ gamma,
                                                 const float* __restrict__ beta,
                                                 unsigned short* __restrict__ out) {
    int wid = threadIdx.x >> 6, lane = threadIdx.x & 63;
    int node = blockIdx.x * 4 + wid;
    int b = node >> 13;
    int i = node & 8191;
    int nid = op_ids[b * 16383 + 8191 + i];
    int ll = leaf_ids[b * 16384 + 2 * i];
    int lr = leaf_ids[b * 16384 + 2 * i + 1];
    const float* c13 = carr + 13 * 256;
    float v[4];
    float s = 0.f, s2 = 0.f;
#pragma unroll
    for (int q = 0; q < 4; q++) {
        int c = q * 64 + lane;
        float x = T0[nid * 256 + c] + T1[ll * 256 + c] + T2[lr * 256 + c] + c13[c];
        x = fmaxf(x, 0.f);
        v[q] = x;
        s += x;
        s2 += x * x;
    }
#pragma unroll
    for (int m = 1; m < 64; m <<= 1) {
        s += __shfl_xor(s, m);
        s2 += __shfl_xor(s2, m);
    }
    float mu = s * (1.f / 256.f);
    float var = s2 * (1.f / 256.f) - mu * mu;
    float rs = rsqrtf(var + 1e-5f);
    unsigned short* o = out + (long)node * 256;
#pragma unroll
    for (int q = 0; q < 4; q++) {
        int c = q * 64 + lane;
        float y = (v[q] - mu) * rs * gamma[c] + beta[c];
        o[c] = f2bf(y);
    }
}

// ---------------- Levels 12..7: MFMA GEMM + gather + relu + LN (B from WTbf sec 1..2)
__global__ __launch_bounds__(256) void k_level(const unsigned short* __restrict__ ebuf_prev,
                                               unsigned short* __restrict__ ebuf_out,
                                               const int* __restrict__ op_ids,
                                               const float* __restrict__ T0,
                                               const float* __restrict__ carr_d,
                                               const float* __restrict__ gamma,
                                               const float* __restrict__ beta,
                                               const unsigned short* __restrict__ WTbf,
                                               int n) {
    int wid = threadIdx.x >> 6, lane = threadIdx.x & 63;
    int b = blockIdx.y;
    int row0 = blockIdx.x * 64;
    int l15 = lane & 15, l4 = lane >> 4;

    __shared__ int s_nid[64];
    __shared__ float s_part[4][64][2];

    if (threadIdx.x < 64) {
        int i = row0 + threadIdx.x;
        int id = 0;
        if (i < n) id = op_ids[b * 16383 + (n - 1) + i];
        s_nid[threadIdx.x] = id;
    }
    __syncthreads();

    const unsigned short* X = ebuf_prev + (long)b * (2 * (long)n) * 256;

    f32x4 acc[4][4] = {};

    for (int kk = 0; kk < 16; kk++) {
        int k0 = kk * 32 + l4 * 8;
        int hi = k0 >> 8;
        int innerk = k0 & 255;
        bf16x8 af[4], bfr[4];
#pragma unroll
        for (int mi = 0; mi < 4; mi++) {
            int r = row0 + mi * 16 + l15;
            af[mi] = *(const bf16x8*)(X + (long)r * 512 + k0);
        }
        const unsigned short* Wb = WTbf + (long)(256 + hi * 256) * 256;
#pragma unroll
        for (int ni = 0; ni < 4; ni++) {
            int cn = wid * 64 + ni * 16 + l15;
            bfr[ni] = *(const bf16x8*)(Wb + (long)cn * 256 + innerk);
        }
#pragma unroll
        for (int mi = 0; mi < 4; mi++)
#pragma unroll
            for (int ni = 0; ni < 4; ni++)
                acc[mi][ni] = __builtin_amdgcn_mfma_f32_16x16x32_bf16(af[mi], bfr[ni],
                                                                     acc[mi][ni], 0, 0, 0);
    }

    float cv[4], gv[4], bv[4];
#pragma unroll
    for (int ni = 0; ni < 4; ni++) {
        int c = wid * 64 + ni * 16 + l15;
        cv[ni] = carr_d[c];
        gv[ni] = gamma[c];
        bv[ni] = beta[c];
    }

#pragma unroll
    for (int mi = 0; mi < 4; mi++) {
#pragma unroll
        for (int r = 0; r < 4; r++) {
            int row = mi * 16 + l4 * 4 + r;
            int nid = s_nid[row];
            float s = 0.f, s2 = 0.f;
#pragma unroll
            for (int ni = 0; ni < 4; ni++) {
                int c = wid * 64 + ni * 16 + l15;
                float h = acc[mi][ni][r] + T0[nid * 256 + c] + cv[ni];
                h = fmaxf(h, 0.f);
                acc[mi][ni][r] = h;
                s += h;
                s2 += h * h;
            }
#pragma unroll
            for (int m = 1; m < 16; m <<= 1) {
                s += __shfl_xor(s, m);
                s2 += __shfl_xor(s2, m);
            }
            if (l15 == 0) {
                s_part[wid][row][0] = s;
                s_part[wid][row][1] = s2;
            }
        }
    }
    __syncthreads();

#pragma unroll
    for (int mi = 0; mi < 4; mi++) {
#pragma unroll
        for (int r = 0; r < 4; r++) {
            int row = mi * 16 + l4 * 4 + r;
            float s = s_part[0][row][0] + s_part[1][row][0] + s_part[2][row][0] + s_part[3][row][0];
            float s2 = s_part[0][row][1] + s_part[1][row][1] + s_part[2][row][1] + s_part[3][row][1];
            float mu = s * (1.f / 256.f);
            float rs = rsqrtf(s2 * (1.f / 256.f) - mu * mu + 1e-5f);
            int i = row0 + row;
            if (i < n) {
                unsigned short* o = ebuf_out + ((long)b * n + i) * 256;
#pragma unroll
                for (int ni = 0; ni < 4; ni++) {
                    int c = wid * 64 + ni * 16 + l15;
                    o[c] = f2bf((acc[mi][ni][r] - mu) * rs * gv[ni] + bv[ni]);
                }
            }
        }
    }
}

// ---------------- Fused tail: levels d=6..0, one block per batch, LDS ping-pong
__global__ __launch_bounds__(256) void k_tail(const unsigned short* __restrict__ prev,
                                              const int* __restrict__ op_ids,
                                              const float* __restrict__ T0,
                                              const float* __restrict__ carr,
                                              const float* __restrict__ gamma,
                                              const float* __restrict__ beta,
                                              const unsigned short* __restrict__ WTbf,
                                              float* __restrict__ out) {
    __shared__ unsigned short sA[128 * 256];
    __shared__ unsigned short sB[64 * 256];
    __shared__ int s_nid[64];
    __shared__ float s_part[4][64][2];
    int b = blockIdx.x;
    int wid = threadIdx.x >> 6, lane = threadIdx.x & 63;
    int l15 = lane & 15, l4 = lane >> 4;

    // stage level-7 output (128 nodes x 256 bf16) into sA, XOR-swizzled
    const unsigned short* src = prev + (long)b * 128 * 256;
#pragma unroll
    for (int p = 0; p < 16; p++) {
        int c = p * 256 + threadIdx.x;  // 16B chunk 0..4095
        int node = c >> 5;
        int byteinrow = (c & 31) * 16;
        bf16x8 v = *(const bf16x8*)(src + c * 8);
        int off = node * 512 + (byteinrow ^ (((node >> 1) & 7) << 4));
        *(bf16x8*)((char*)sA + off) = v;
    }

    float gv[4], bv[4];
#pragma unroll
    for (int ni = 0; ni < 4; ni++) {
        int c = wid * 64 + ni * 16 + l15;
        gv[ni] = gamma[c];
        bv[ni] = beta[c];
    }

    unsigned short* cur = sA;
    unsigned short* nxt = sB;
    for (int ld = 6; ld >= 0; ld--) {
        int n = 1 << ld;
        if (threadIdx.x < n) s_nid[threadIdx.x] = op_ids[b * 16383 + (n - 1) + threadIdx.x];
        __syncthreads();
        int mtiles = (n + 15) >> 4;

        f32x4 acc[4][4] = {};
        for (int kk = 0; kk < 16; kk++) {
            int k0 = kk * 32 + l4 * 8;
            int hi = k0 >> 8;
            int binr = (k0 & 255) * 2;
            bf16x8 af[4], bfr[4];
#pragma unroll
            for (int mi = 0; mi < 4; mi++) {
                if (mi < mtiles) {
                    int i = mi * 16 + l15;
                    int node = 2 * i + hi;
                    int off = node * 512 + (binr ^ (((node >> 1) & 7) << 4));
                    af[mi] = *(const bf16x8*)((const char*)cur + off);
                }
            }
            const unsigned short* Wb = WTbf + (long)(256 + hi * 256) * 256;
            int innerk = k0 & 255;
#pragma unroll
            for (int ni = 0; ni < 4; ni++) {
                int cn = wid * 64 + ni * 16 + l15;
                bfr[ni] = *(const bf16x8*)(Wb + (long)cn * 256 + innerk);
            }
#pragma unroll
            for (int mi = 0; mi < 4; mi++)
                if (mi < mtiles)
#pragma unroll
                    for (int ni = 0; ni < 4; ni++)
                        acc[mi][ni] = __builtin_amdgcn_mfma_f32_16x16x32_bf16(af[mi], bfr[ni],
                                                                             acc[mi][ni], 0, 0, 0);
        }

        const float* carr_d = carr + ld * 256;
        float cv[4];
#pragma unroll
        for (int ni = 0; ni < 4; ni++) cv[ni] = carr_d[wid * 64 + ni * 16 + l15];

#pragma unroll
        for (int mi = 0; mi < 4; mi++) {
            if (mi >= mtiles) continue;
#pragma unroll
            for (int r = 0; r < 4; r++) {
                int row = mi * 16 + l4 * 4 + r;
                int nid = s_nid[row & 63];
                float s = 0.f, s2 = 0.f;
#pragma unroll
                for (int ni = 0; ni < 4; ni++) {
                    int c = wid * 64 + ni * 16 + l15;
                    float h = acc[mi][ni][r] + T0[nid * 256 + c] + cv[ni];
                    h = fmaxf(h, 0.f);
                    acc[mi][ni][r] = h;
                    s += h;
                    s2 += h * h;
                }
#pragma unroll
                for (int m = 1; m < 16; m <<= 1) {
                    s += __shfl_xor(s, m);
                    s2 += __shfl_xor(s2, m);
                }
                if (l15 == 0) {
                    s_part[wid][row][0] = s;
                    s_part[wid][row][1] = s2;
                }
            }
        }
        __syncthreads();

#pragma unroll
        for (int mi = 0; mi < 4; mi++) {
            if (mi >= mtiles) continue;
#pragma unroll
            for (int r = 0; r < 4; r++) {
                int row = mi * 16 + l4 * 4 + r;
                if (row >= n) continue;
                float s = s_part[0][row][0] + s_part[1][row][0] + s_part[2][row][0] + s_part[3][row][0];
                float s2 = s_part[0][row][1] + s_part[1][row][1] + s_part[2][row][1] + s_part[3][row][1];
                float mu = s * (1.f / 256.f);
                float rs = rsqrtf(s2 * (1.f / 256.f) - mu * mu + 1e-5f);
                if (ld == 0) {
                    if (row == 0) {
#pragma unroll
                        for (int ni = 0; ni < 4; ni++) {
                            int c = wid * 64 + ni * 16 + l15;
                            out[b * 256 + c] = (acc[mi][ni][r] - mu) * rs * gv[ni] + bv[ni];
                        }
                    }
                } else {
#pragma unroll
                    for (int ni = 0; ni < 4; ni++) {
                        int c = wid * 64 + ni * 16 + l15;
                        unsigned short val = f2bf((acc[mi][ni][r] - mu) * rs * gv[ni] + bv[ni]);
                        int off = row * 512 + ((c * 2) ^ (((row >> 1) & 7) << 4));
                        *(unsigned short*)((char*)nxt + off) = val;
                    }
                }
            }
        }
        unsigned short* t = cur;
        cur = nxt;
        nxt = t;
    }
}

extern "C" void kernel_launch(void* const* d_in, const int* in_sizes, int n_in,
                              void* d_out, int out_size, void* d_ws, size_t ws_size,
                              hipStream_t stream) {
    const int* leaf_ids = (const int*)d_in[0];
    const int* op_ids = (const int*)d_in[1];
    const float* tok = (const float*)d_in[2];
    const float* dep = (const float*)d_in[3];
    const float* idx = (const float*)d_in[4];
    const float* W = (const float*)d_in[5];
    const float* bvec = (const float*)d_in[6];
    const float* gamma = (const float*)d_in[7];
    const float* beta = (const float*)d_in[8];
    float* out = (float*)d_out;

    char* ws = (char*)d_ws;
    float* T0 = (float*)(ws);                                            // 3 MB (T0,T1,T2)
    unsigned short* WTbf = (unsigned short*)(ws + 3u * 1024 * 1024);     // 384 KB
    unsigned short* tokbf = (unsigned short*)(ws + 3u * 1024 * 1024 + 512 * 1024);  // 512 KB
    float* carr = (float*)(ws + 4u * 1024 * 1024 + 64 * 1024);           // 14 KB
    unsigned short* ebufA = (unsigned short*)(ws + 8u * 1024 * 1024);    // 32 MB
    unsigned short* ebufB = (unsigned short*)(ws + 40u * 1024 * 1024);   // 16 MB

    k_prep_tok<<<256, 256, 0, stream>>>(tok, tokbf);
    k_prep_wt<<<48, 256, 0, stream>>>(W, WTbf);
    k_ttmm<<<dim3(16, 3), 256, 0, stream>>>(tokbf, WTbf, T0);
    k_carr<<<14, 256, 0, stream>>>(dep, idx, W, bvec, carr);

    k_level13<<<16384, 256, 0, stream>>>(leaf_ids, op_ids, T0, T0 + 1024 * 256,
                                         T0 + 2 * 1024 * 256, carr, gamma, beta, ebufA);

    unsigned short* prev = ebufA;
    unsigned short* next = ebufB;
    for (int d = 12; d >= 7; d--) {
        int n = 1 << d;
        dim3 grid(n / 64, 8);
        k_level<<<grid, 256, 0, stream>>>(prev, next, op_ids, T0, carr + d * 256, gamma, beta,
                                          WTbf, n);
        unsigned short* t = prev;
        prev = next;
        next = t;
    }

    k_tail<<<8, 256, 0, stream>>>(prev, op_ids, T0, carr, gamma, beta, WTbf, out);
}

// Round 3
// 300.685 us; speedup vs baseline: 1.5264x; 1.1143x over previous
//
#include <hip/hip_runtime.h>

typedef float f32x4 __attribute__((ext_vector_type(4)));
typedef short bf16x8 __attribute__((ext_vector_type(8)));

__device__ inline unsigned short f2bf(float f) {
    unsigned int u = __builtin_bit_cast(unsigned int, f);
    unsigned int r = (u + 0x7FFFu + ((u >> 16) & 1u)) >> 16;
    return (unsigned short)r;
}

// ---------------- Combined prep: tok->bf16 | W transpose->bf16 | carr vectors
__global__ __launch_bounds__(256) void k_prep(const float* __restrict__ tok,
                                              const float* __restrict__ W,
                                              const float* __restrict__ dep,
                                              const float* __restrict__ idx,
                                              const float* __restrict__ bvec,
                                              unsigned short* __restrict__ tokbf,
                                              unsigned short* __restrict__ WTbf,
                                              float* __restrict__ carr) {
    __shared__ float s_tile[64][65];
    int bx = blockIdx.x;
    if (bx < 256) {
        int i = bx * 256 + threadIdx.x;
        const float4 v = *(const float4*)(tok + (long)i * 4);
        ushort4 o;
        o.x = f2bf(v.x); o.y = f2bf(v.y); o.z = f2bf(v.z); o.w = f2bf(v.w);
        *(ushort4*)(tokbf + (long)i * 4) = o;
    } else if (bx < 304) {
        int bb = bx - 256;
        int sec = bb >> 4;
        int tt = bb & 15;
        int k0 = (tt >> 2) * 64, j0 = (tt & 3) * 64;
        int tx = threadIdx.x & 63, ty = threadIdx.x >> 6;
#pragma unroll
        for (int r = 0; r < 16; r++) {
            int kk = ty * 16 + r;
            s_tile[kk][tx] = W[(sec * 256 + k0 + kk) * 256 + j0 + tx];
        }
        __syncthreads();
#pragma unroll
        for (int r = 0; r < 16; r++) {
            int jj = ty * 16 + r;
            WTbf[(sec * 256 + j0 + jj) * 256 + k0 + tx] = f2bf(s_tile[tx][jj]);
        }
    } else {
        int d = bx - 304;
        int j = threadIdx.x;
        float acc = bvec[j];
#pragma unroll 4
        for (int k = 0; k < 256; k++) {
            float dv = dep[(d + 1) * 256 + k];
            acc += dv * (W[(768 + k) * 256 + j] + W[(1280 + k) * 256 + j]);
            acc += idx[k] * W[(1024 + k) * 256 + j];
            acc += idx[256 + k] * W[(1536 + k) * 256 + j];
        }
        if (d == 13) {
#pragma unroll 4
            for (int k = 0; k < 256; k++) {
                float dv = dep[14 * 256 + k];
                acc += dv * (W[(256 + k) * 256 + j] + W[(512 + k) * 256 + j]);
            }
        }
        carr[d * 256 + j] = acc;
    }
}

// ---------------- T tables via MFMA: T[sec][1024][256] = tokbf @ Wsec (32-row blocks)
__global__ __launch_bounds__(256) void k_ttmm(const unsigned short* __restrict__ tokbf,
                                              const unsigned short* __restrict__ WTbf,
                                              float* __restrict__ T) {
    int wid = threadIdx.x >> 6, lane = threadIdx.x & 63;
    int l15 = lane & 15, l4 = lane >> 4;
    int row0 = blockIdx.x * 32;
    int sec = blockIdx.y;

    f32x4 acc[2][4] = {};
    for (int kk = 0; kk < 8; kk++) {
        int k0 = kk * 32 + l4 * 8;
        bf16x8 af[2], bfr[4];
#pragma unroll
        for (int mi = 0; mi < 2; mi++)
            af[mi] = *(const bf16x8*)(tokbf + (long)(row0 + mi * 16 + l15) * 256 + k0);
#pragma unroll
        for (int ni = 0; ni < 4; ni++)
            bfr[ni] = *(const bf16x8*)(WTbf + (long)(sec * 256 + wid * 64 + ni * 16 + l15) * 256 + k0);
#pragma unroll
        for (int mi = 0; mi < 2; mi++)
#pragma unroll
            for (int ni = 0; ni < 4; ni++)
                acc[mi][ni] = __builtin_amdgcn_mfma_f32_16x16x32_bf16(af[mi], bfr[ni],
                                                                     acc[mi][ni], 0, 0, 0);
    }
#pragma unroll
    for (int mi = 0; mi < 2; mi++)
#pragma unroll
        for (int r = 0; r < 4; r++) {
            int row = row0 + mi * 16 + l4 * 4 + r;
#pragma unroll
            for (int ni = 0; ni < 4; ni++) {
                int c = wid * 64 + ni * 16 + l15;
                T[(long)sec * 262144 + (long)row * 256 + c] = acc[mi][ni][r];
            }
        }
}

// ---------------- Fused level 13+12: gather/LN level-13 into LDS, then GEMM level-12
__global__ __launch_bounds__(256) void k_level12f(const int* __restrict__ leaf_ids,
                                                  const int* __restrict__ op_ids,
                                                  const float* __restrict__ T,
                                                  const float* __restrict__ carr,
                                                  const float* __restrict__ gamma,
                                                  const float* __restrict__ beta,
                                                  const unsigned short* __restrict__ WTbf,
                                                  unsigned short* __restrict__ ebuf_out) {
    __shared__ unsigned short sA[128 * 256];
    __shared__ int s_nid13[128];
    __shared__ int s_leaf[256];
    __shared__ int s_nid[64];
    __shared__ float s_part[4][64][2];
    int b = blockIdx.y;
    int row0 = blockIdx.x * 64;
    int t = threadIdx.x;
    int wid = t >> 6, lane = t & 63;
    int l15 = lane & 15, l4 = lane >> 4;
    const float* T0 = T;
    const float* T1 = T + 262144;
    const float* T2 = T + 524288;

    if (t < 128) s_nid13[t] = op_ids[b * 16383 + 8191 + 2 * row0 + t];
    s_leaf[t] = leaf_ids[b * 16384 + 4 * row0 + t];
    if (t < 64) s_nid[t] = op_ids[b * 16383 + 4095 + row0 + t];
    __syncthreads();

    {
        const float* c13 = carr + 13 * 256;
        float4 dd = *(const float4*)(c13 + 4 * lane);
        float4 g4 = *(const float4*)(gamma + 4 * lane);
        float4 b4 = *(const float4*)(beta + 4 * lane);
#pragma unroll 2
        for (int j = 0; j < 32; j++) {
            int node = wid * 32 + j;
            int nid = s_nid13[node];
            int ll = s_leaf[2 * node], lr = s_leaf[2 * node + 1];
            float4 a = *(const float4*)(T0 + (long)nid * 256 + 4 * lane);
            float4 bb = *(const float4*)(T1 + (long)ll * 256 + 4 * lane);
            float4 cc = *(const float4*)(T2 + (long)lr * 256 + 4 * lane);
            float v0 = fmaxf(a.x + bb.x + cc.x + dd.x, 0.f);
            float v1 = fmaxf(a.y + bb.y + cc.y + dd.y, 0.f);
            float v2 = fmaxf(a.z + bb.z + cc.z + dd.z, 0.f);
            float v3 = fmaxf(a.w + bb.w + cc.w + dd.w, 0.f);
            float s = v0 + v1 + v2 + v3;
            float s2 = v0 * v0 + v1 * v1 + v2 * v2 + v3 * v3;
#pragma unroll
            for (int m = 1; m < 64; m <<= 1) {
                s += __shfl_xor(s, m);
                s2 += __shfl_xor(s2, m);
            }
            float mu = s * (1.f / 256.f);
            float rs = rsqrtf(s2 * (1.f / 256.f) - mu * mu + 1e-5f);
            ushort4 o;
            o.x = f2bf((v0 - mu) * rs * g4.x + b4.x);
            o.y = f2bf((v1 - mu) * rs * g4.y + b4.y);
            o.z = f2bf((v2 - mu) * rs * g4.z + b4.z);
            o.w = f2bf((v3 - mu) * rs * g4.w + b4.w);
            *(ushort4*)((char*)sA + node * 512 + ((8 * lane) ^ (((node >> 1) & 7) << 4))) = o;
        }
    }
    __syncthreads();

    f32x4 acc[4][4] = {};
    for (int kk = 0; kk < 16; kk++) {
        int k0 = kk * 32 + l4 * 8;
        int hi = k0 >> 8;
        int binr = (k0 & 255) * 2;
        bf16x8 af[4], bfr[4];
#pragma unroll
        for (int mi = 0; mi < 4; mi++) {
            int node = 2 * (mi * 16 + l15) + hi;
            af[mi] = *(const bf16x8*)((const char*)sA + node * 512 + (binr ^ (((node >> 1) & 7) << 4)));
        }
        const unsigned short* Wb = WTbf + (long)(256 + hi * 256) * 256;
        int innerk = k0 & 255;
#pragma unroll
        for (int ni = 0; ni < 4; ni++) {
            int cn = wid * 64 + ni * 16 + l15;
            bfr[ni] = *(const bf16x8*)(Wb + (long)cn * 256 + innerk);
        }
#pragma unroll
        for (int mi = 0; mi < 4; mi++)
#pragma unroll
            for (int ni = 0; ni < 4; ni++)
                acc[mi][ni] = __builtin_amdgcn_mfma_f32_16x16x32_bf16(af[mi], bfr[ni],
                                                                     acc[mi][ni], 0, 0, 0);
    }

    const float* carr_d = carr + 12 * 256;
    float cv[4], gv[4], bv[4];
#pragma unroll
    for (int ni = 0; ni < 4; ni++) {
        int c = wid * 64 + ni * 16 + l15;
        cv[ni] = carr_d[c];
        gv[ni] = gamma[c];
        bv[ni] = beta[c];
    }

#pragma unroll
    for (int mi = 0; mi < 4; mi++) {
#pragma unroll
        for (int r = 0; r < 4; r++) {
            int row = mi * 16 + l4 * 4 + r;
            int nid = s_nid[row];
            float s = 0.f, s2 = 0.f;
#pragma unroll
            for (int ni = 0; ni < 4; ni++) {
                int c = wid * 64 + ni * 16 + l15;
                float h = acc[mi][ni][r] + T0[(long)nid * 256 + c] + cv[ni];
                h = fmaxf(h, 0.f);
                acc[mi][ni][r] = h;
                s += h;
                s2 += h * h;
            }
#pragma unroll
            for (int m = 1; m < 16; m <<= 1) {
                s += __shfl_xor(s, m);
                s2 += __shfl_xor(s2, m);
            }
            if (l15 == 0) {
                s_part[wid][row][0] = s;
                s_part[wid][row][1] = s2;
            }
        }
    }
    __syncthreads();

#pragma unroll
    for (int mi = 0; mi < 4; mi++) {
#pragma unroll
        for (int r = 0; r < 4; r++) {
            int row = mi * 16 + l4 * 4 + r;
            float s = s_part[0][row][0] + s_part[1][row][0] + s_part[2][row][0] + s_part[3][row][0];
            float s2 = s_part[0][row][1] + s_part[1][row][1] + s_part[2][row][1] + s_part[3][row][1];
            float mu = s * (1.f / 256.f);
            float rs = rsqrtf(s2 * (1.f / 256.f) - mu * mu + 1e-5f);
            unsigned short* o = ebuf_out + ((long)b * 4096 + row0 + row) * 256;
#pragma unroll
            for (int ni = 0; ni < 4; ni++) {
                int c = wid * 64 + ni * 16 + l15;
                o[c] = f2bf((acc[mi][ni][r] - mu) * rs * gv[ni] + bv[ni]);
            }
        }
    }
}

// ---------------- Levels 11..7: MFMA GEMM + gather + relu + LN (MT*16 rows per block)
template <int MT>
__global__ __launch_bounds__(256) void k_level(const unsigned short* __restrict__ ebuf_prev,
                                               unsigned short* __restrict__ ebuf_out,
                                               const int* __restrict__ op_ids,
                                               const float* __restrict__ T0,
                                               const float* __restrict__ carr_d,
                                               const float* __restrict__ gamma,
                                               const float* __restrict__ beta,
                                               const unsigned short* __restrict__ WTbf,
                                               int n) {
    int wid = threadIdx.x >> 6, lane = threadIdx.x & 63;
    int b = blockIdx.y;
    int row0 = blockIdx.x * (MT * 16);
    int l15 = lane & 15, l4 = lane >> 4;

    __shared__ int s_nid[MT * 16];
    __shared__ float s_part[4][MT * 16][2];

    if (threadIdx.x < MT * 16)
        s_nid[threadIdx.x] = op_ids[b * 16383 + (n - 1) + row0 + threadIdx.x];
    __syncthreads();

    const unsigned short* X = ebuf_prev + (long)b * (2 * (long)n) * 256;

    f32x4 acc[MT][4] = {};

    for (int kk = 0; kk < 16; kk++) {
        int k0 = kk * 32 + l4 * 8;
        int hi = k0 >> 8;
        int innerk = k0 & 255;
        bf16x8 af[MT], bfr[4];
#pragma unroll
        for (int mi = 0; mi < MT; mi++) {
            int r = row0 + mi * 16 + l15;
            af[mi] = *(const bf16x8*)(X + (long)r * 512 + k0);
        }
        const unsigned short* Wb = WTbf + (long)(256 + hi * 256) * 256;
#pragma unroll
        for (int ni = 0; ni < 4; ni++) {
            int cn = wid * 64 + ni * 16 + l15;
            bfr[ni] = *(const bf16x8*)(Wb + (long)cn * 256 + innerk);
        }
#pragma unroll
        for (int mi = 0; mi < MT; mi++)
#pragma unroll
            for (int ni = 0; ni < 4; ni++)
                acc[mi][ni] = __builtin_amdgcn_mfma_f32_16x16x32_bf16(af[mi], bfr[ni],
                                                                     acc[mi][ni], 0, 0, 0);
    }

    float cv[4], gv[4], bv[4];
#pragma unroll
    for (int ni = 0; ni < 4; ni++) {
        int c = wid * 64 + ni * 16 + l15;
        cv[ni] = carr_d[c];
        gv[ni] = gamma[c];
        bv[ni] = beta[c];
    }

#pragma unroll
    for (int mi = 0; mi < MT; mi++) {
#pragma unroll
        for (int r = 0; r < 4; r++) {
            int row = mi * 16 + l4 * 4 + r;
            int nid = s_nid[row];
            float s = 0.f, s2 = 0.f;
#pragma unroll
            for (int ni = 0; ni < 4; ni++) {
                int c = wid * 64 + ni * 16 + l15;
                float h = acc[mi][ni][r] + T0[(long)nid * 256 + c] + cv[ni];
                h = fmaxf(h, 0.f);
                acc[mi][ni][r] = h;
                s += h;
                s2 += h * h;
            }
#pragma unroll
            for (int m = 1; m < 16; m <<= 1) {
                s += __shfl_xor(s, m);
                s2 += __shfl_xor(s2, m);
            }
            if (l15 == 0) {
                s_part[wid][row][0] = s;
                s_part[wid][row][1] = s2;
            }
        }
    }
    __syncthreads();

#pragma unroll
    for (int mi = 0; mi < MT; mi++) {
#pragma unroll
        for (int r = 0; r < 4; r++) {
            int row = mi * 16 + l4 * 4 + r;
            float s = s_part[0][row][0] + s_part[1][row][0] + s_part[2][row][0] + s_part[3][row][0];
            float s2 = s_part[0][row][1] + s_part[1][row][1] + s_part[2][row][1] + s_part[3][row][1];
            float mu = s * (1.f / 256.f);
            float rs = rsqrtf(s2 * (1.f / 256.f) - mu * mu + 1e-5f);
            unsigned short* o = ebuf_out + ((long)b * n + row0 + row) * 256;
#pragma unroll
            for (int ni = 0; ni < 4; ni++) {
                int c = wid * 64 + ni * 16 + l15;
                o[c] = f2bf((acc[mi][ni][r] - mu) * rs * gv[ni] + bv[ni]);
            }
        }
    }
}

// ---------------- Fused tail: levels 6..0, 8 blocks x 512 threads, T0 prefetch
__global__ __launch_bounds__(512) void k_tail(const unsigned short* __restrict__ prev,
                                              const int* __restrict__ op_ids,
                                              const float* __restrict__ T0,
                                              const float* __restrict__ carr,
                                              const float* __restrict__ gamma,
                                              const float* __restrict__ beta,
                                              const unsigned short* __restrict__ WTbf,
                                              float* __restrict__ out) {
    __shared__ unsigned short sA[128 * 256];
    __shared__ unsigned short sB[64 * 256];
    __shared__ int s_nid_all[127];
    __shared__ float s_part[8][64][2];
    int b = blockIdx.x;
    int t = threadIdx.x;
    int wid = t >> 6, lane = t & 63;
    int l15 = lane & 15, l4 = lane >> 4;

    if (t < 127) s_nid_all[t] = op_ids[b * 16383 + t];
    const unsigned short* src = prev + (long)b * 128 * 256;
#pragma unroll
    for (int p = 0; p < 8; p++) {
        int c = p * 512 + t;
        int node = c >> 5;
        int binr = (c & 31) * 16;
        bf16x8 v = *(const bf16x8*)(src + (long)c * 8);
        *(bf16x8*)((char*)sA + node * 512 + (binr ^ (((node >> 1) & 7) << 4))) = v;
    }
    float gv[2], bv[2];
#pragma unroll
    for (int ni = 0; ni < 2; ni++) {
        int c = wid * 32 + ni * 16 + l15;
        gv[ni] = gamma[c];
        bv[ni] = beta[c];
    }
    __syncthreads();

    unsigned short* cur = sA;
    unsigned short* nxt = sB;
    for (int ld = 6; ld >= 0; ld--) {
        int n = 1 << ld;
        int mtiles = (n + 15) >> 4;

        // prefetch epilogue T0 values (independent of level chain)
        float tv[4][4][2];
#pragma unroll
        for (int mi = 0; mi < 4; mi++)
            if (mi < mtiles)
#pragma unroll
                for (int r = 0; r < 4; r++) {
                    int row = mi * 16 + l4 * 4 + r;
                    int rc = row < n ? row : n - 1;
                    int nid = s_nid_all[(n - 1) + rc];
#pragma unroll
                    for (int ni = 0; ni < 2; ni++)
                        tv[mi][r][ni] = T0[(long)nid * 256 + wid * 32 + ni * 16 + l15];
                }

        f32x4 acc[4][2] = {};
        for (int kk = 0; kk < 16; kk++) {
            int k0 = kk * 32 + l4 * 8;
            int hi = k0 >> 8;
            int binr = (k0 & 255) * 2;
            bf16x8 af[4], bfr[2];
#pragma unroll
            for (int mi = 0; mi < 4; mi++)
                if (mi < mtiles) {
                    int node = 2 * (mi * 16 + l15) + hi;
                    af[mi] = *(const bf16x8*)((const char*)cur + node * 512 +
                                              (binr ^ (((node >> 1) & 7) << 4)));
                }
            const unsigned short* Wb = WTbf + (long)(256 + hi * 256) * 256;
            int innerk = k0 & 255;
#pragma unroll
            for (int ni = 0; ni < 2; ni++) {
                int cn = wid * 32 + ni * 16 + l15;
                bfr[ni] = *(const bf16x8*)(Wb + (long)cn * 256 + innerk);
            }
#pragma unroll
            for (int mi = 0; mi < 4; mi++)
                if (mi < mtiles)
#pragma unroll
                    for (int ni = 0; ni < 2; ni++)
                        acc[mi][ni] = __builtin_amdgcn_mfma_f32_16x16x32_bf16(af[mi], bfr[ni],
                                                                             acc[mi][ni], 0, 0, 0);
        }

        const float* carr_d = carr + ld * 256;
        float cv[2];
#pragma unroll
        for (int ni = 0; ni < 2; ni++) cv[ni] = carr_d[wid * 32 + ni * 16 + l15];

#pragma unroll
        for (int mi = 0; mi < 4; mi++)
            if (mi < mtiles)
#pragma unroll
                for (int r = 0; r < 4; r++) {
                    float s = 0.f, s2 = 0.f;
#pragma unroll
                    for (int ni = 0; ni < 2; ni++) {
                        float h = acc[mi][ni][r] + tv[mi][r][ni] + cv[ni];
                        h = fmaxf(h, 0.f);
                        acc[mi][ni][r] = h;
                        s += h;
                        s2 += h * h;
                    }
#pragma unroll
                    for (int m = 1; m < 16; m <<= 1) {
                        s += __shfl_xor(s, m);
                        s2 += __shfl_xor(s2, m);
                    }
                    if (l15 == 0) {
                        int row = mi * 16 + l4 * 4 + r;
                        s_part[wid][row][0] = s;
                        s_part[wid][row][1] = s2;
                    }
                }
        __syncthreads();

#pragma unroll
        for (int mi = 0; mi < 4; mi++)
            if (mi < mtiles)
#pragma unroll
                for (int r = 0; r < 4; r++) {
                    int row = mi * 16 + l4 * 4 + r;
                    if (row < n) {
                        float s = 0.f, s2 = 0.f;
#pragma unroll
                        for (int w = 0; w < 8; w++) {
                            s += s_part[w][row][0];
                            s2 += s_part[w][row][1];
                        }
                        float mu = s * (1.f / 256.f);
                        float rs = rsqrtf(s2 * (1.f / 256.f) - mu * mu + 1e-5f);
                        if (ld == 0) {
                            if (row == 0) {
#pragma unroll
                                for (int ni = 0; ni < 2; ni++) {
                                    int c = wid * 32 + ni * 16 + l15;
                                    out[b * 256 + c] = (acc[mi][ni][r] - mu) * rs * gv[ni] + bv[ni];
                                }
                            }
                        } else {
#pragma unroll
                            for (int ni = 0; ni < 2; ni++) {
                                int c = wid * 32 + ni * 16 + l15;
                                unsigned short val = f2bf((acc[mi][ni][r] - mu) * rs * gv[ni] + bv[ni]);
                                *(unsigned short*)((char*)nxt + row * 512 +
                                                   ((c * 2) ^ (((row >> 1) & 7) << 4))) = val;
                            }
                        }
                    }
                }
        __syncthreads();
        unsigned short* tmp = cur;
        cur = nxt;
        nxt = tmp;
    }
}

extern "C" void kernel_launch(void* const* d_in, const int* in_sizes, int n_in,
                              void* d_out, int out_size, void* d_ws, size_t ws_size,
                              hipStream_t stream) {
    const int* leaf_ids = (const int*)d_in[0];
    const int* op_ids = (const int*)d_in[1];
    const float* tok = (const float*)d_in[2];
    const float* dep = (const float*)d_in[3];
    const float* idx = (const float*)d_in[4];
    const float* W = (const float*)d_in[5];
    const float* bvec = (const float*)d_in[6];
    const float* gamma = (const float*)d_in[7];
    const float* beta = (const float*)d_in[8];
    float* out = (float*)d_out;

    char* ws = (char*)d_ws;
    float* T = (float*)(ws);                                             // 3 MB (T0|T1|T2)
    unsigned short* WTbf = (unsigned short*)(ws + 3u * 1024 * 1024);     // 384 KB
    unsigned short* tokbf = (unsigned short*)(ws + 3u * 1024 * 1024 + 512 * 1024);  // 512 KB
    float* carr = (float*)(ws + 4u * 1024 * 1024 + 64 * 1024);           // 14 KB
    unsigned short* ebufA = (unsigned short*)(ws + 8u * 1024 * 1024);    // 16 MB
    unsigned short* ebufB = (unsigned short*)(ws + 40u * 1024 * 1024);   // 8 MB

    k_prep<<<318, 256, 0, stream>>>(tok, W, dep, idx, bvec, tokbf, WTbf, carr);
    k_ttmm<<<dim3(32, 3), 256, 0, stream>>>(tokbf, WTbf, T);

    k_level12f<<<dim3(64, 8), 256, 0, stream>>>(leaf_ids, op_ids, T, carr, gamma, beta, WTbf,
                                                ebufA);

    k_level<4><<<dim3(32, 8), 256, 0, stream>>>(ebufA, ebufB, op_ids, T, carr + 11 * 256, gamma,
                                                beta, WTbf, 2048);
    k_level<2><<<dim3(32, 8), 256, 0, stream>>>(ebufB, ebufA, op_ids, T, carr + 10 * 256, gamma,
                                                beta, WTbf, 1024);
    k_level<2><<<dim3(16, 8), 256, 0, stream>>>(ebufA, ebufB, op_ids, T, carr + 9 * 256, gamma,
                                                beta, WTbf, 512);
    k_level<2><<<dim3(8, 8), 256, 0, stream>>>(ebufB, ebufA, op_ids, T, carr + 8 * 256, gamma,
                                               beta, WTbf, 256);
    k_level<2><<<dim3(4, 8), 256, 0, stream>>>(ebufA, ebufB, op_ids, T, carr + 7 * 256, gamma,
                                               beta, WTbf, 128);

    k_tail<<<8, 512, 0, stream>>>(ebufB, op_ids, T, carr, gamma, beta, WTbf, out);
}